// Round 1
// baseline (13938.200 us; speedup 1.0000x reference)
//
#include <hip/hip_runtime.h>
#include <math.h>
#include <cstddef>

#define N_PTS 131072
#define SDIM  512
#define D1    513

static constexpr int NITER = 100;
static constexpr int BLK   = 512;            // 8 waves / block
static constexpr int GRID  = 512;            // 2 blocks / CU
static constexpr int WPB   = BLK / 64;       // waves per block
static constexpr int TW    = GRID * WPB;     // 4096 waves
static constexpr int RPW   = N_PTS / TW;     // 32 rows per wave

struct Ws {
  double acc[514];        // [0..511] spatial sums, [512] time sum, [513] cc sum
  unsigned int counter;
  unsigned int pad;
  float mean[513];        // [0] = time coordinate
};

template<bool INIT>
__device__ void finalize_wave(Ws* ws, int l)
{
  if constexpr (INIT) {
    double r[9]; double s2 = 0.0;
    #pragma unroll
    for (int q = 0; q < 9; ++q) {
      int c = q * 64 + l;
      r[q] = 0.0;
      if (c < D1) {
        double sv = ws->acc[(c == 0) ? 512 : (c - 1)];
        r[q] = sv / (double)N_PTS;
        s2 += r[q] * r[q];
      }
    }
    #pragma unroll
    for (int m = 1; m < 64; m <<= 1) s2 += __shfl_xor(s2, m);
    double r0 = __shfl(r[0], 0);
    double inv = 1.0 / sqrt(fabs(s2 - 2.0 * r0 * r0));
    #pragma unroll
    for (int q = 0; q < 9; ++q) {
      int c = q * 64 + l;
      if (c < D1) ws->mean[c] = (float)(r[q] * inv);
    }
  } else {
    double cc = ws->acc[513];
    double mv[9], yv[9]; double sy = 0.0;
    #pragma unroll
    for (int q = 0; q < 9; ++q) {
      int c = q * 64 + l;
      mv[q] = 0.0; yv[q] = 0.0;
      if (c < D1) {
        double m  = (double)ws->mean[c];
        double sv = ws->acc[(c == 0) ? 512 : (c - 1)];
        double y  = 0.02 * (sv - cc * m) / (double)N_PTS;  // y = -R*g, R=0.01
        mv[q] = m; yv[q] = y;
        sy += y * y;
      }
    }
    #pragma unroll
    for (int m = 1; m < 64; m <<= 1) sy += __shfl_xor(sy, m);
    double y0 = __shfl(yv[0], 0);
    double n = sqrt(fabs(sy - 2.0 * y0 * y0));
    n = fmax(n, 1e-5);
    double ch = cosh(n);
    double sn = (n < 1e-4) ? (1.0 + n * n / 6.0) : (sinh(n) / n);
    double nm[9]; double s2 = 0.0;
    #pragma unroll
    for (int q = 0; q < 9; ++q) {
      int c = q * 64 + l;
      nm[q] = 0.0;
      if (c < D1) {
        nm[q] = ch * mv[q] + sn * yv[q];
        s2 += nm[q] * nm[q];
      }
    }
    #pragma unroll
    for (int m = 1; m < 64; m <<= 1) s2 += __shfl_xor(s2, m);
    double m0n = __shfl(nm[0], 0);
    double inv = 1.0 / sqrt(fabs(s2 - 2.0 * m0n * m0n));
    #pragma unroll
    for (int q = 0; q < 9; ++q) {
      int c = q * 64 + l;
      if (c < D1) ws->mean[c] = (float)(nm[q] * inv);
    }
  }
  // zero accumulators for the next pass
  #pragma unroll
  for (int q = 0; q < 9; ++q) {
    int c = q * 64 + l;
    if (c < 514) ws->acc[c] = 0.0;
  }
}

template<bool INIT>
__global__ __launch_bounds__(BLK)
void reduce_kernel(const float* __restrict__ data, Ws* __restrict__ ws, int rev)
{
  const int lane = threadIdx.x & 63;
  const int wid  = threadIdx.x >> 6;
  const int gw   = blockIdx.x * WPB + wid;

  float m0 = 0.f;
  float mk0=0.f, mk1=0.f, mk2=0.f, mk3=0.f, mk4=0.f, mk5=0.f, mk6=0.f, mk7=0.f;
  if constexpr (!INIT) {
    m0 = ws->mean[0];
    const float* msp = ws->mean + 1;
    mk0 = msp[lane*4 + 0]; mk1 = msp[lane*4 + 1];
    mk2 = msp[lane*4 + 2]; mk3 = msp[lane*4 + 3];
    mk4 = msp[256 + lane*4 + 0]; mk5 = msp[256 + lane*4 + 1];
    mk6 = msp[256 + lane*4 + 2]; mk7 = msp[256 + lane*4 + 3];
  }

  double a0=0,a1=0,a2=0,a3=0,a4=0,a5=0,a6=0,a7=0;
  double acc_t = 0.0, acc_cc = 0.0;

  #pragma unroll 2
  for (int k = 0; k < RPW; ++k) {
    int rr  = gw * RPW + k;
    int row = rev ? (N_PTS - 1 - rr) : rr;
    const float4* p4 = (const float4*)(data + (size_t)row * SDIM);
    float4 v0 = p4[lane];        // cols lane*4 .. +3
    float4 v1 = p4[64 + lane];   // cols 256+lane*4 .. +3

    float sq = v0.x * v0.x;
    sq = fmaf(v0.y, v0.y, sq);
    sq = fmaf(v0.z, v0.z, sq);
    sq = fmaf(v0.w, v0.w, sq);
    sq = fmaf(v1.x, v1.x, sq);
    sq = fmaf(v1.y, v1.y, sq);
    sq = fmaf(v1.z, v1.z, sq);
    sq = fmaf(v1.w, v1.w, sq);

    float dot = 0.f;
    if constexpr (!INIT) {
      dot = v0.x * mk0;
      dot = fmaf(v0.y, mk1, dot);
      dot = fmaf(v0.z, mk2, dot);
      dot = fmaf(v0.w, mk3, dot);
      dot = fmaf(v1.x, mk4, dot);
      dot = fmaf(v1.y, mk5, dot);
      dot = fmaf(v1.z, mk6, dot);
      dot = fmaf(v1.w, mk7, dot);
    }

    #pragma unroll
    for (int m = 1; m < 64; m <<= 1) {
      sq += __shfl_xor(sq, m);
      if constexpr (!INIT) dot += __shfl_xor(dot, m);
    }

    float t = sqrtf(1.0f + sq);
    float c1;
    if constexpr (INIT) {
      c1 = 1.0f;
    } else {
      float a = m0 * t - dot;          // -mdot(mean, p_i)
      float x = fmaxf(a, 1.0f + 1e-5f);
      float s = sqrtf(x * x - 1.0f);   // sinh(d)
      float d = logf(x + s);           // arccosh(x)
      c1 = d / s;                      // d / sinh(d)
      acc_cc += (double)c1 * (double)x;  // c1 * cosh(d)
    }
    acc_t += (double)c1 * (double)t;

    double c1d = (double)c1;
    a0 = fma(c1d, (double)v0.x, a0);
    a1 = fma(c1d, (double)v0.y, a1);
    a2 = fma(c1d, (double)v0.z, a2);
    a3 = fma(c1d, (double)v0.w, a3);
    a4 = fma(c1d, (double)v1.x, a4);
    a5 = fma(c1d, (double)v1.y, a5);
    a6 = fma(c1d, (double)v1.z, a6);
    a7 = fma(c1d, (double)v1.w, a7);
  }

  // block-level reduction across waves in LDS
  __shared__ double s_red[WPB][514];
  {
    int b = lane * 4;
    s_red[wid][b + 0] = a0; s_red[wid][b + 1] = a1;
    s_red[wid][b + 2] = a2; s_red[wid][b + 3] = a3;
    s_red[wid][256 + b + 0] = a4; s_red[wid][256 + b + 1] = a5;
    s_red[wid][256 + b + 2] = a6; s_red[wid][256 + b + 3] = a7;
    if (lane == 0) { s_red[wid][512] = acc_t; s_red[wid][513] = acc_cc; }
  }
  __syncthreads();

  for (int c = threadIdx.x; c < 514; c += BLK) {
    double s = 0.0;
    #pragma unroll
    for (int w = 0; w < WPB; ++w) s += s_red[w][c];
    atomicAdd(&ws->acc[c], s);
  }
  __threadfence();
  __syncthreads();

  __shared__ unsigned int s_ticket;
  if (threadIdx.x == 0) s_ticket = atomicAdd(&ws->counter, 1u);
  __syncthreads();

  if (s_ticket == (unsigned)(GRID - 1)) {
    __threadfence();   // acquire: make all blocks' atomics visible, invalidate L1
    if (threadIdx.x < 64) finalize_wave<INIT>(ws, threadIdx.x);
    if (threadIdx.x == 0) ws->counter = 0u;
  }
}

__global__ void write_out_kernel(const float* __restrict__ mean, float* __restrict__ out)
{
  int i = threadIdx.x;
  if (i < SDIM) out[i] = mean[1 + i];
}

extern "C" void kernel_launch(void* const* d_in, const int* in_sizes, int n_in,
                              void* d_out, int out_size, void* d_ws, size_t ws_size,
                              hipStream_t stream)
{
  (void)in_sizes; (void)n_in; (void)out_size; (void)ws_size;
  const float* data = (const float*)d_in[0];
  Ws* ws = (Ws*)d_ws;

  // zero accumulators + ticket counter (mean is fully written by the init pass)
  hipMemsetAsync(d_ws, 0, offsetof(Ws, mean), stream);

  // init pass: mean = normalize(mean over N of projected)
  reduce_kernel<true><<<dim3(GRID), dim3(BLK), 0, stream>>>(data, ws, 0);

  // 100 fixed-point iterations; alternate sweep direction for L3 reuse
  for (int it = 0; it < NITER; ++it) {
    reduce_kernel<false><<<dim3(GRID), dim3(BLK), 0, stream>>>(data, ws, (it & 1) ^ 1);
  }

  float* meanp = (float*)((char*)d_ws + offsetof(Ws, mean));
  write_out_kernel<<<dim3(1), dim3(512), 0, stream>>>(meanp, (float*)d_out);
}